// Round 4
// baseline (1517.463 us; speedup 1.0000x reference)
//
#include <hip/hip_runtime.h>
#include <hip/hip_cooperative_groups.h>
#include <math.h>

namespace cg = cooperative_groups;

#define N_NODES 100000
#define D_IN 256
#define H1 16
#define H2 32
#define BSHIFT 6                 // 64 rows per bucket
#define BROWS 64
#define NB 1563                  // ceil(N_NODES / 64)
#define NT1 782                  // ceil(N_NODES / 128) xw1 tiles
#define HB 160                   // blocks doing histogram in phase A1
#define CH 8192                  // edges per scatter chunk

// ---------- bf16 helpers (manual, RNE) ----------
static __device__ __forceinline__ float bf_lo(unsigned int u) {
    return __uint_as_float(u << 16);
}
static __device__ __forceinline__ float bf_hi(unsigned int u) {
    return __uint_as_float(u & 0xffff0000u);
}
static __device__ __forceinline__ unsigned int f2bf_rne(float f) {
    unsigned int u = __float_as_uint(f);
    return (u + 0x7fffu + ((u >> 16) & 1u)) >> 16;
}
static __device__ __forceinline__ unsigned int pack_bf16(float lo, float hi) {
    return f2bf_rne(lo) | (f2bf_rne(hi) << 16);
}
static __device__ __forceinline__ unsigned int cvt_pk_bf16(float lo, float hi) {
    unsigned int r;
    asm("v_cvt_pk_bf16_f32 %0, %1, %2" : "=v"(r) : "v"(lo), "v"(hi));
    return r;
}

typedef __attribute__((ext_vector_type(8))) short bf16x8;
typedef __attribute__((ext_vector_type(4))) float f32x4;
union ABFrag { unsigned int u[4]; bf16x8 v; };

// ---------------- shared xw1 tile worker (proven in r2, absmax 0) ---------
// MFMA 16x16x32 bf16. A: row=l&15, k=(l>>4)*8+e; B: col=l&15 same k;
// D: col=l&15, row=(l>>4)*4+reg.
static __device__ __forceinline__ void xw1_block(const float* __restrict__ x,
                                                 const float* __restrict__ W1,
                                                 unsigned short* __restrict__ t,
                                                 int tt, int tid) {
    const int lane = tid & 63;
    const int wid  = tid >> 6;
    const int fcol = lane & 15;
    const int kgrp = lane >> 4;

    ABFrag bfrag[8];
#pragma unroll
    for (int g = 0; g < 8; g++) {
        const float* wp = W1 + (g * 32 + kgrp * 8) * H1 + fcol;
#pragma unroll
        for (int p = 0; p < 4; p++)
            bfrag[g].u[p] = cvt_pk_bf16(wp[(2 * p) * H1], wp[(2 * p + 1) * H1]);
    }

    const int wrow0 = tt * 128 + wid * 32;
#pragma unroll
    for (int tile = 0; tile < 2; tile++) {
        const int row0 = wrow0 + tile * 16;
        int arow = row0 + fcol;
        if (arow >= N_NODES) arow = N_NODES - 1;
        const float* xr = x + (size_t)arow * D_IN;
        f32x4 acc = {0.f, 0.f, 0.f, 0.f};
#pragma unroll
        for (int g = 0; g < 8; g++) {
            const float4 a0 = *(const float4*)(xr + g * 32 + kgrp * 8);
            const float4 a1 = *(const float4*)(xr + g * 32 + kgrp * 8 + 4);
            ABFrag af;
            af.u[0] = cvt_pk_bf16(a0.x, a0.y);
            af.u[1] = cvt_pk_bf16(a0.z, a0.w);
            af.u[2] = cvt_pk_bf16(a1.x, a1.y);
            af.u[3] = cvt_pk_bf16(a1.z, a1.w);
            acc = __builtin_amdgcn_mfma_f32_16x16x32_bf16(af.v, bfrag[g].v, acc, 0, 0, 0);
        }
#pragma unroll
        for (int r = 0; r < 4; r++) {
            int orow = row0 + kgrp * 4 + r;
            if (orow < N_NODES)
                t[(size_t)orow * H1 + fcol] = (unsigned short)f2bf_rne(acc[r]);
        }
    }
}

// ---------------- mega-kernel LDS (union across phases) -------------------
union MegaSmem {
    int lh[NB];                                   // A1 hist (6252 B)
    struct { int lcount[NB]; int lbase[NB]; } sc; // C scatter (12504 B)
    float gs[BROWS * H1];                         // D gacc (4096 B)
    int scan[256];                                // B scan
    float red[4][16];                             // E reduce
};

__global__ __launch_bounds__(256, 4) void k_mega(
    const float* __restrict__ x, const float* __restrict__ edge_vals,
    const float* __restrict__ W1, const float* __restrict__ W2,
    const float* __restrict__ w_out, const float* __restrict__ b_out,
    const int* __restrict__ edge_rows, const int* __restrict__ edge_cols,
    float* __restrict__ out,
    unsigned short* __restrict__ t, unsigned int* __restrict__ g2,
    float* __restrict__ s, int* __restrict__ base, int* __restrict__ hist,
    unsigned int* __restrict__ cursor, int* __restrict__ hist_priv,
    uint2* __restrict__ ed, int E)
{
    cg::grid_group grid = cg::this_grid();
    const int tid = threadIdx.x;
    const int bid = blockIdx.x;
    const int G   = gridDim.x;
    __shared__ MegaSmem sm;

    // ---- A1: xw1 (blocks [HB,G)) in parallel with private hists [0,HB) ----
    if (bid == 0 && tid < 16) s[tid] = 0.f;
    if (bid < HB) {
        for (int b = tid; b < NB; b += 256) sm.lh[b] = 0;
        __syncthreads();
        for (int i = bid * 256 + tid; i < E; i += HB * 256)
            atomicAdd(&sm.lh[edge_rows[i] >> BSHIFT], 1);
        __syncthreads();
        for (int b = tid; b < NB; b += 256) hist_priv[bid * NB + b] = sm.lh[b];
    } else {
        for (int tt = bid - HB; tt < NT1; tt += (G - HB))
            xw1_block(x, W1, t, tt, tid);
    }
    __threadfence(); grid.sync(); __threadfence();

    // ---- A2: reduce private hists -> hist ----
    for (int b = bid * 256 + tid; b < NB; b += G * 256) {
        int sum = 0;
#pragma unroll 4
        for (int p = 0; p < HB; p++) sum += hist_priv[p * NB + b];
        hist[b] = sum;
    }
    __threadfence(); grid.sync(); __threadfence();

    // ---- B: exclusive scan (block 0), init base + cursors ----
    if (bid == 0) {
        int loc[7]; int mysum = 0;
#pragma unroll
        for (int j = 0; j < 7; j++) {
            int b = tid * 7 + j;
            int h = (b < NB) ? hist[b] : 0;
            loc[j] = mysum; mysum += h;
        }
        sm.scan[tid] = mysum;
        __syncthreads();
        int incl = mysum;
        for (int off = 1; off < 256; off <<= 1) {
            int add = (tid >= off) ? sm.scan[tid - off] : 0;
            __syncthreads();
            incl += add; sm.scan[tid] = incl;
            __syncthreads();
        }
        int excl = incl - mysum;
#pragma unroll
        for (int j = 0; j < 7; j++) {
            int b = tid * 7 + j;
            if (b < NB) {
                int v = excl + loc[j];
                base[b] = v;
                cursor[b * 8] = (unsigned int)v;   // 32B-padded cursors
            }
        }
        if (tid == 255) base[NB] = incl;
    }
    __threadfence(); grid.sync(); __threadfence();

    // ---- C: scatter edges into bucket lists (8B packed) ----
    const int nch = (E + CH - 1) / CH;
    for (int ch = bid; ch < nch; ch += G) {
        const int c0 = ch * CH;
        const int c1 = min(c0 + CH, E);
        for (int b = tid; b < NB; b += 256) sm.sc.lcount[b] = 0;
        __syncthreads();
        for (int i = c0 + tid; i < c1; i += 256)
            atomicAdd(&sm.sc.lcount[edge_rows[i] >> BSHIFT], 1);
        __syncthreads();
        for (int b = tid; b < NB; b += 256) {
            int c = sm.sc.lcount[b];
            sm.sc.lbase[b] = c ? (int)atomicAdd(&cursor[b * 8], (unsigned int)c) : 0;
            sm.sc.lcount[b] = 0;
        }
        __syncthreads();
        for (int i = c0 + tid; i < c1; i += 256) {
            int r = edge_rows[i];
            int b = r >> BSHIFT;
            int rank = atomicAdd(&sm.sc.lcount[b], 1);
            int pos = sm.sc.lbase[b] + rank;
            ed[pos] = make_uint2(((unsigned int)edge_cols[i] << BSHIFT) |
                                     (unsigned int)(r & (BROWS - 1)),
                                 __float_as_uint(edge_vals[i]));
        }
        __syncthreads();
    }
    __threadfence(); grid.sync(); __threadfence();

    // ---- D: per-bucket g accumulation in LDS f32, write bf16 g2 ----
    const unsigned int* tp = (const unsigned int*)t;
    for (int b = bid; b < NB; b += G) {
        for (int i = tid; i < BROWS * H1; i += 256) sm.gs[i] = 0.f;
        __syncthreads();
        const int e0 = base[b], e1 = base[b + 1];
        const int f2 = tid & 7, grp = tid >> 3;   // 32 edge streams per block
        for (int i = e0 + grp; i < e1; i += 32) {
            uint2 e = ed[i];
            int c  = (int)(e.x >> BSHIFT);
            int r6 = (int)(e.x & (BROWS - 1));
            float v = __uint_as_float(e.y);
            unsigned int tv = tp[c * 8 + f2];
            atomicAdd(&sm.gs[r6 * H1 + 2 * f2],     v * bf_lo(tv));
            atomicAdd(&sm.gs[r6 * H1 + 2 * f2 + 1], v * bf_hi(tv));
        }
        __syncthreads();
        const int row0 = b << BSHIFT;
        for (int j = tid; j < BROWS * H1 / 2; j += 256) {   // 512 packed u32
            int row = j >> 3, fp = j & 7;
            int grow = row0 + row;
            if (grow < N_NODES)
                g2[grow * 8 + fp] = pack_bf16(sm.gs[row * H1 + 2 * fp],
                                              sm.gs[row * H1 + 2 * fp + 1]);
        }
        __syncthreads();
    }
    __threadfence(); grid.sync(); __threadfence();

    // ---- E: s[f] = sum_e val[e] * relu(g[col[e]])[f] ----
    {
        const int f2 = tid & 7;
        int idx    = (bid * 256 + tid) >> 3;
        int stride = G * 32;
        float accl = 0.f, acch = 0.f;
        for (int e = idx; e < E; e += stride) {
            int c = edge_cols[e];
            float v = edge_vals[e];
            unsigned int gv = g2[c * 8 + f2];
            accl = fmaf(v, fmaxf(bf_lo(gv), 0.f), accl);
            acch = fmaf(v, fmaxf(bf_hi(gv), 0.f), acch);
        }
        accl += __shfl_xor(accl, 8, 64);
        accl += __shfl_xor(accl, 16, 64);
        accl += __shfl_xor(accl, 32, 64);
        acch += __shfl_xor(acch, 8, 64);
        acch += __shfl_xor(acch, 16, 64);
        acch += __shfl_xor(acch, 32, 64);
        int lane = tid & 63, wid = tid >> 6;
        __syncthreads();
        if (lane < 8) { sm.red[wid][2 * lane] = accl; sm.red[wid][2 * lane + 1] = acch; }
        __syncthreads();
        if (tid < 16) {
            float v = sm.red[0][tid] + sm.red[1][tid] + sm.red[2][tid] + sm.red[3][tid];
            atomicAdd(&s[tid], v);
        }
    }
    __threadfence(); grid.sync(); __threadfence();

    // ---- F: out = sigmoid((s @ W2) @ w_out + b_out) ----
    if (bid == 0 && tid < 64) {
        int f2 = tid;
        float m = 0.f;
        if (f2 < H2) {
            float v = 0.f;
#pragma unroll
            for (int f1 = 0; f1 < H1; f1++) v = fmaf(s[f1], W2[f1 * H2 + f2], v);
            m = v * w_out[f2];
        }
        for (int off = 32; off; off >>= 1) m += __shfl_down(m, off, 64);
        if (f2 == 0) out[0] = 1.f / (1.f + expf(-(m + b_out[0])));
    }
}

// ====================== fallback path (round-2 proven) ======================
__global__ void k_zero(float4* __restrict__ p, int n4) {
    int i = blockIdx.x * blockDim.x + threadIdx.x;
    if (i < n4) p[i] = make_float4(0.f, 0.f, 0.f, 0.f);
}

__global__ __launch_bounds__(256) void k_xw1(const float* __restrict__ x,
                                             const float* __restrict__ W1,
                                             unsigned short* __restrict__ t) {
    xw1_block(x, W1, t, blockIdx.x, threadIdx.x);
}

__global__ __launch_bounds__(256) void k_edge(const int* __restrict__ rows,
                                              const int* __restrict__ cols,
                                              const float* __restrict__ vals,
                                              const unsigned int* __restrict__ tb,
                                              unsigned int* __restrict__ g2, int E) {
    int tid = blockIdx.x * 256 + threadIdx.x;
    int e = tid >> 3;
    int f2 = tid & 7;
    if (e >= E) return;
    int r = rows[e];
    int c = cols[e];
    float v = vals[e];
    unsigned int tv = tb[c * 8 + f2];
    unsigned int pk = pack_bf16(v * bf_lo(tv), v * bf_hi(tv));
    unsigned int* addr = g2 + (r * 8 + f2);
    asm volatile("global_atomic_pk_add_bf16 %0, %1, off"
                 :: "v"(addr), "v"(pk) : "memory");
}

__global__ __launch_bounds__(256) void k_s2(const int* __restrict__ cols,
                                            const float* __restrict__ vals,
                                            const unsigned int* __restrict__ g2,
                                            float* __restrict__ s, int E) {
    const int f2 = threadIdx.x & 7;
    int idx    = (blockIdx.x * 256 + threadIdx.x) >> 3;
    int stride = (gridDim.x * 256) >> 3;
    float accl = 0.f, acch = 0.f;
    for (int e = idx; e < E; e += stride) {
        int c = cols[e];
        float v = vals[e];
        unsigned int gv = g2[c * 8 + f2];
        accl = fmaf(v, fmaxf(bf_lo(gv), 0.f), accl);
        acch = fmaf(v, fmaxf(bf_hi(gv), 0.f), acch);
    }
    accl += __shfl_xor(accl, 8, 64);
    accl += __shfl_xor(accl, 16, 64);
    accl += __shfl_xor(accl, 32, 64);
    acch += __shfl_xor(acch, 8, 64);
    acch += __shfl_xor(acch, 16, 64);
    acch += __shfl_xor(acch, 32, 64);
    __shared__ float red[4][16];
    int lane = threadIdx.x & 63, wid = threadIdx.x >> 6;
    if (lane < 8) { red[wid][2 * lane] = accl; red[wid][2 * lane + 1] = acch; }
    __syncthreads();
    if (threadIdx.x < 16) {
        float v = red[0][threadIdx.x] + red[1][threadIdx.x] +
                  red[2][threadIdx.x] + red[3][threadIdx.x];
        atomicAdd(&s[threadIdx.x], v);
    }
}

__global__ void k_out(const float* __restrict__ s, const float* __restrict__ W2,
                      const float* __restrict__ w_out,
                      const float* __restrict__ b_out,
                      float* __restrict__ out) {
    int f2 = threadIdx.x;
    float m = 0.f;
    if (f2 < H2) {
        float v = 0.f;
#pragma unroll
        for (int f1 = 0; f1 < H1; f1++) v = fmaf(s[f1], W2[f1 * H2 + f2], v);
        m = v * w_out[f2];
    }
    for (int off = 32; off; off >>= 1) m += __shfl_down(m, off, 64);
    if (f2 == 0) out[0] = 1.f / (1.f + expf(-(m + b_out[0])));
}

extern "C" void kernel_launch(void* const* d_in, const int* in_sizes, int n_in,
                              void* d_out, int out_size, void* d_ws, size_t ws_size,
                              hipStream_t stream) {
    const float* x         = (const float*)d_in[0];
    const float* edge_vals = (const float*)d_in[1];
    const float* W1        = (const float*)d_in[2];
    const float* W2        = (const float*)d_in[3];
    const float* w_out     = (const float*)d_in[4];
    const float* b_out     = (const float*)d_in[5];
    const int*   edge_rows = (const int*)d_in[6];
    const int*   edge_cols = (const int*)d_in[7];
    float* out = (float*)d_out;

    const int E = in_sizes[1];   // 3.2M

    // ---- mega workspace layout (bytes, 64B-aligned fields) ----
    //   t:         [0,          3,200,000)
    //   g2:        [3,200,000,  6,400,000)
    //   s:         [6,400,000,  6,400,064)
    //   base:      [6,400,064,  6,406,336)   (NB+1) ints
    //   hist:      [6,406,336,  6,412,608)   NB ints
    //   cursor:    [6,412,608,  6,462,656)   NB * 32B
    //   hist_priv: [6,462,656,  7,463,040)   HB*NB ints
    //   ed:        [7,463,040, 33,063,040)   E * 8B
    char* ws = (char*)d_ws;
    unsigned short* t    = (unsigned short*)(ws);
    unsigned int*   g2   = (unsigned int*)(ws + 3200000);
    float*          s    = (float*)(ws + 6400000);
    int*            base = (int*)(ws + 6400064);
    int*            hist = (int*)(ws + 6406336);
    unsigned int*   cur  = (unsigned int*)(ws + 6412608);
    int*            hp   = (int*)(ws + 6462656);
    uint2*          ed   = (uint2*)(ws + 7463040);

    bool mega_ok = (ws_size >= 33100000) && (E <= 3200000);
    if (mega_ok) {
        static int grid_blocks = 0;
        if (grid_blocks == 0) {
            int maxb = 0;
            if (hipOccupancyMaxActiveBlocksPerMultiprocessor(
                    &maxb, (const void*)k_mega, 256, 0) != hipSuccess || maxb < 1)
                maxb = 2;
            int ncu = 256, dev = 0;
            hipDeviceProp_t prop;
            if (hipGetDevice(&dev) == hipSuccess &&
                hipGetDeviceProperties(&prop, dev) == hipSuccess)
                ncu = prop.multiProcessorCount;
            grid_blocks = maxb * ncu;
            if (grid_blocks > 2048) grid_blocks = 2048;
            if (grid_blocks < 256)  grid_blocks = 256;
        }
        void* args[] = {(void*)&x, (void*)&edge_vals, (void*)&W1, (void*)&W2,
                        (void*)&w_out, (void*)&b_out, (void*)&edge_rows,
                        (void*)&edge_cols, (void*)&out, (void*)&t, (void*)&g2,
                        (void*)&s, (void*)&base, (void*)&hist, (void*)&cur,
                        (void*)&hp, (void*)&ed, (void*)&E};
        hipError_t err = hipLaunchCooperativeKernel(
            (const void*)k_mega, dim3(grid_blocks), dim3(256), args, 0, stream);
        if (err != hipSuccess) mega_ok = false;
    }

    if (!mega_ok) {
        // round-2 proven path; its own layout: g2@0, s@3.2M, t@3.2M+64
        unsigned int*   fg2 = (unsigned int*)(ws);
        float*          fs  = (float*)(ws + 3200000);
        unsigned short* ft  = (unsigned short*)(ws + 3200064);
        k_zero<<<(200004 + 255) / 256, 256, 0, stream>>>((float4*)ws, 200004);
        k_xw1<<<NT1, 256, 0, stream>>>(x, W1, ft);
        long long edge_threads = (long long)E * 8;
        k_edge<<<(int)((edge_threads + 255) / 256), 256, 0, stream>>>(
            edge_rows, edge_cols, edge_vals, (const unsigned int*)ft, fg2, E);
        k_s2<<<1024, 256, 0, stream>>>(edge_cols, edge_vals, fg2, fs, E);
        k_out<<<1, 64, 0, stream>>>(fs, W2, w_out, b_out, out);
    }
}

// Round 5
// 415.840 us; speedup vs baseline: 3.6492x; 3.6492x over previous
//
#include <hip/hip_runtime.h>
#include <math.h>

#define N_NODES 100000
#define D_IN 256
#define H1 16
#define H2 32
#define NT1 782                  // ceil(N_NODES / 128) xw1 tiles

// ---------- bf16 helpers (manual, RNE) ----------
static __device__ __forceinline__ float bf_lo(unsigned int u) {
    return __uint_as_float(u << 16);
}
static __device__ __forceinline__ float bf_hi(unsigned int u) {
    return __uint_as_float(u & 0xffff0000u);
}
static __device__ __forceinline__ unsigned int f2bf_rne(float f) {
    unsigned int u = __float_as_uint(f);
    return (u + 0x7fffu + ((u >> 16) & 1u)) >> 16;
}
static __device__ __forceinline__ unsigned int pack_bf16(float lo, float hi) {
    return f2bf_rne(lo) | (f2bf_rne(hi) << 16);
}
static __device__ __forceinline__ unsigned int cvt_pk_bf16(float lo, float hi) {
    unsigned int r;
    asm("v_cvt_pk_bf16_f32 %0, %1, %2" : "=v"(r) : "v"(lo), "v"(hi));
    return r;
}

typedef __attribute__((ext_vector_type(8))) short bf16x8;
typedef __attribute__((ext_vector_type(4))) float f32x4;
union ABFrag { unsigned int u[4]; bf16x8 v; };

// ---------------- xw1 tile worker (r2-proven, absmax 0) -------------------
// MFMA 16x16x32 bf16. A: row=l&15, k=(l>>4)*8+e; B: col=l&15 same k;
// D: col=l&15, row=(l>>4)*4+reg.
static __device__ __forceinline__ void xw1_block(const float* __restrict__ x,
                                                 const float* __restrict__ W1,
                                                 unsigned short* __restrict__ t,
                                                 int tt, int tid) {
    const int lane = tid & 63;
    const int wid  = tid >> 6;
    const int fcol = lane & 15;
    const int kgrp = lane >> 4;

    ABFrag bfrag[8];
#pragma unroll
    for (int g = 0; g < 8; g++) {
        const float* wp = W1 + (g * 32 + kgrp * 8) * H1 + fcol;
#pragma unroll
        for (int p = 0; p < 4; p++)
            bfrag[g].u[p] = cvt_pk_bf16(wp[(2 * p) * H1], wp[(2 * p + 1) * H1]);
    }

    const int wrow0 = tt * 128 + wid * 32;
#pragma unroll
    for (int tile = 0; tile < 2; tile++) {
        const int row0 = wrow0 + tile * 16;
        int arow = row0 + fcol;
        if (arow >= N_NODES) arow = N_NODES - 1;   // clamp for safe loads
        const float* xr = x + (size_t)arow * D_IN;
        f32x4 acc = {0.f, 0.f, 0.f, 0.f};
#pragma unroll
        for (int g = 0; g < 8; g++) {
            const float4 a0 = *(const float4*)(xr + g * 32 + kgrp * 8);
            const float4 a1 = *(const float4*)(xr + g * 32 + kgrp * 8 + 4);
            ABFrag af;
            af.u[0] = cvt_pk_bf16(a0.x, a0.y);
            af.u[1] = cvt_pk_bf16(a0.z, a0.w);
            af.u[2] = cvt_pk_bf16(a1.x, a1.y);
            af.u[3] = cvt_pk_bf16(a1.z, a1.w);
            acc = __builtin_amdgcn_mfma_f32_16x16x32_bf16(af.v, bfrag[g].v, acc, 0, 0, 0);
        }
#pragma unroll
        for (int r = 0; r < 4; r++) {
            int orow = row0 + kgrp * 4 + r;
            if (orow < N_NODES)
                t[(size_t)orow * H1 + fcol] = (unsigned short)f2bf_rne(acc[r]);
        }
    }
}

// ---------------- launch 1: t = bf16(x@W1), fused zero of g2/s/flag -------
__global__ __launch_bounds__(256) void k_xw1z(const float* __restrict__ x,
                                              const float* __restrict__ W1,
                                              unsigned short* __restrict__ t,
                                              float4* __restrict__ g2z,
                                              float* __restrict__ s,
                                              unsigned int* __restrict__ flag) {
    const int tid = threadIdx.x;
    const int bid = blockIdx.x;
    // zero g2 (200,000 float4 over 782*256=200,192 threads: <=1 store each)
    int zi = bid * 256 + tid;
    if (zi < 200000) g2z[zi] = make_float4(0.f, 0.f, 0.f, 0.f);
    if (bid == 0) {
        if (tid < 16) s[tid] = 0.f;
        if (tid == 16) *flag = 0u;
    }
    xw1_block(x, W1, t, bid, tid);
}

// ---------------- launch 2: g[r] += val * t[c] (r2-proven, at atomic wall) -
__global__ __launch_bounds__(256) void k_edge(const int* __restrict__ rows,
                                              const int* __restrict__ cols,
                                              const float* __restrict__ vals,
                                              const unsigned int* __restrict__ tb,
                                              unsigned int* __restrict__ g2, int E) {
    int tid = blockIdx.x * 256 + threadIdx.x;
    int e = tid >> 3;
    int f2 = tid & 7;
    if (e >= E) return;
    int r = rows[e];
    int c = cols[e];
    float v = vals[e];
    unsigned int tv = tb[c * 8 + f2];
    unsigned int pk = pack_bf16(v * bf_lo(tv), v * bf_hi(tv));
    unsigned int* addr = g2 + (r * 8 + f2);
    asm volatile("global_atomic_pk_add_bf16 %0, %1, off"
                 :: "v"(addr), "v"(pk) : "memory");
}

// ---------------- launch 3: s[f]=sum_e val*relu(g[col]); last block: out ---
__global__ __launch_bounds__(256) void k_s2out(const int* __restrict__ cols,
                                               const float* __restrict__ vals,
                                               const unsigned int* __restrict__ g2,
                                               float* __restrict__ s,
                                               unsigned int* __restrict__ flag,
                                               const float* __restrict__ W2,
                                               const float* __restrict__ w_out,
                                               const float* __restrict__ b_out,
                                               float* __restrict__ out, int E) {
    const int tid = threadIdx.x;
    const int f2 = tid & 7;
    int idx    = (blockIdx.x * 256 + tid) >> 3;
    int stride = (gridDim.x * 256) >> 3;
    float accl = 0.f, acch = 0.f;
    for (int e = idx; e < E; e += stride) {
        int c = cols[e];
        float v = vals[e];
        unsigned int gv = g2[c * 8 + f2];
        accl = fmaf(v, fmaxf(bf_lo(gv), 0.f), accl);
        acch = fmaf(v, fmaxf(bf_hi(gv), 0.f), acch);
    }
    accl += __shfl_xor(accl, 8, 64);
    accl += __shfl_xor(accl, 16, 64);
    accl += __shfl_xor(accl, 32, 64);
    acch += __shfl_xor(acch, 8, 64);
    acch += __shfl_xor(acch, 16, 64);
    acch += __shfl_xor(acch, 32, 64);
    __shared__ float red[4][16];
    __shared__ int slast;
    int lane = tid & 63, wid = tid >> 6;
    if (lane < 8) { red[wid][2 * lane] = accl; red[wid][2 * lane + 1] = acch; }
    __syncthreads();
    if (tid < 16) {
        float v = red[0][tid] + red[1][tid] + red[2][tid] + red[3][tid];
        atomicAdd(&s[tid], v);
    }
    // ---- last-block-done detection, then fused k_out ----
    if (tid == 0) {
        __threadfence();                          // make s-adds visible
        unsigned int old = atomicAdd(flag, 1u);
        slast = (old == gridDim.x - 1) ? 1 : 0;
    }
    __syncthreads();
    if (slast && tid < 64) {
        // coherent read of s via atomic RMW (bypasses stale local caches)
        float sv = (tid < H1) ? atomicAdd(&s[tid], 0.f) : 0.f;
        float m = 0.f;
        if (tid < H2) {
            float v = 0.f;
#pragma unroll
            for (int f1 = 0; f1 < H1; f1++)
                v = fmaf(__shfl(sv, f1, 64), W2[f1 * H2 + tid], v);
            m = v * w_out[tid];
        }
        for (int off = 32; off; off >>= 1) m += __shfl_down(m, off, 64);
        if (tid == 0) out[0] = 1.f / (1.f + expf(-(m + b_out[0])));
    }
}

extern "C" void kernel_launch(void* const* d_in, const int* in_sizes, int n_in,
                              void* d_out, int out_size, void* d_ws, size_t ws_size,
                              hipStream_t stream) {
    const float* x         = (const float*)d_in[0];
    const float* edge_vals = (const float*)d_in[1];
    const float* W1        = (const float*)d_in[2];
    const float* W2        = (const float*)d_in[3];
    const float* w_out     = (const float*)d_in[4];
    const float* b_out     = (const float*)d_in[5];
    const int*   edge_rows = (const int*)d_in[6];
    const int*   edge_cols = (const int*)d_in[7];
    float* out = (float*)d_out;

    const int E = in_sizes[1];   // 3.2M

    // workspace layout (bytes):
    //   t   (bf16): [0,         3,200,000)
    //   g2  (bf16): [3,200,000, 6,400,000)   zeroed in k_xw1z
    //   s   (fp32): [6,400,000, 6,400,064)   zeroed in k_xw1z
    //   flag(u32):  [6,400,128, 6,400,132)   zeroed in k_xw1z
    char* ws = (char*)d_ws;
    unsigned short* t    = (unsigned short*)(ws);
    unsigned int*   g2   = (unsigned int*)(ws + 3200000);
    float*          s    = (float*)(ws + 6400000);
    unsigned int*   flag = (unsigned int*)(ws + 6400128);

    k_xw1z<<<NT1, 256, 0, stream>>>(x, W1, t, (float4*)g2, s, flag);

    long long edge_threads = (long long)E * 8;
    k_edge<<<(int)((edge_threads + 255) / 256), 256, 0, stream>>>(
        edge_rows, edge_cols, edge_vals, (const unsigned int*)t, g2, E);

    k_s2out<<<1024, 256, 0, stream>>>(edge_cols, edge_vals, g2, s, flag,
                                      W2, w_out, b_out, out, E);
}

// Round 6
// 411.936 us; speedup vs baseline: 3.6837x; 1.0095x over previous
//
#include <hip/hip_runtime.h>
#include <math.h>

#define N_NODES 100000
#define D_IN 256
#define H1 16
#define H2 32
#define NT1 1563                 // ceil(N_NODES / 64): one 16-row tile per wave

// ---------- bf16 helpers (manual, RNE) ----------
static __device__ __forceinline__ float bf_lo(unsigned int u) {
    return __uint_as_float(u << 16);
}
static __device__ __forceinline__ float bf_hi(unsigned int u) {
    return __uint_as_float(u & 0xffff0000u);
}
static __device__ __forceinline__ unsigned int f2bf_rne(float f) {
    unsigned int u = __float_as_uint(f);
    return (u + 0x7fffu + ((u >> 16) & 1u)) >> 16;
}
static __device__ __forceinline__ unsigned int pack_bf16(float lo, float hi) {
    return f2bf_rne(lo) | (f2bf_rne(hi) << 16);
}
static __device__ __forceinline__ unsigned int cvt_pk_bf16(float lo, float hi) {
    unsigned int r;
    asm("v_cvt_pk_bf16_f32 %0, %1, %2" : "=v"(r) : "v"(lo), "v"(hi));
    return r;
}

typedef __attribute__((ext_vector_type(8))) short bf16x8;
typedef __attribute__((ext_vector_type(4))) float f32x4;
union ABFrag { unsigned int u[4]; bf16x8 v; };

// ---------------- launch 1: t = bf16(x@W1), fused zero of g2/s/flag -------
// One MFMA 16x16x32 tile (16 rows) per wave; 4 waves/block -> 64 rows/block,
// 1563 blocks (~6/CU). Per lane only 16 independent 16B x-loads -> deep
// latency hiding; kernel floor = 102.4MB / 6.3TB/s ~= 16us.
// Layouts (r2-proven, absmax 0): A: row=l&15, k=(l>>4)*8+e; B: col=l&15
// same k; D: col=l&15, row=(l>>4)*4+reg.
__global__ __launch_bounds__(256) void k_xw1z(const float* __restrict__ x,
                                              const float* __restrict__ W1,
                                              unsigned short* __restrict__ t,
                                              float4* __restrict__ g2z,
                                              float* __restrict__ s,
                                              unsigned int* __restrict__ flag) {
    const int tid = threadIdx.x;
    const int bid = blockIdx.x;

    // fused zeroing: g2 = 200,000 float4 over 1563*256 = 400,128 threads
    int zi = bid * 256 + tid;
    if (zi < 200000) g2z[zi] = make_float4(0.f, 0.f, 0.f, 0.f);
    if (bid == 0) {
        if (tid < 16) s[tid] = 0.f;
        if (tid == 16) *flag = 0u;
    }

    const int lane = tid & 63;
    const int wid  = tid >> 6;
    const int fcol = lane & 15;
    const int kgrp = lane >> 4;

    // B-frags: bfrag[g] covers W1[32g .. 32g+31][0..15] (L2-broadcast loads)
    ABFrag bfrag[8];
#pragma unroll
    for (int g = 0; g < 8; g++) {
        const float* wp = W1 + (g * 32 + kgrp * 8) * H1 + fcol;
#pragma unroll
        for (int p = 0; p < 4; p++)
            bfrag[g].u[p] = cvt_pk_bf16(wp[(2 * p) * H1], wp[(2 * p + 1) * H1]);
    }

    const int row0 = bid * 64 + wid * 16;
    int arow = row0 + fcol;
    if (arow >= N_NODES) arow = N_NODES - 1;   // clamp for safe loads
    const float* xr = x + (size_t)arow * D_IN;
    f32x4 acc = {0.f, 0.f, 0.f, 0.f};
#pragma unroll
    for (int g = 0; g < 8; g++) {
        const float4 a0 = *(const float4*)(xr + g * 32 + kgrp * 8);
        const float4 a1 = *(const float4*)(xr + g * 32 + kgrp * 8 + 4);
        ABFrag af;
        af.u[0] = cvt_pk_bf16(a0.x, a0.y);
        af.u[1] = cvt_pk_bf16(a0.z, a0.w);
        af.u[2] = cvt_pk_bf16(a1.x, a1.y);
        af.u[3] = cvt_pk_bf16(a1.z, a1.w);
        acc = __builtin_amdgcn_mfma_f32_16x16x32_bf16(af.v, bfrag[g].v, acc, 0, 0, 0);
    }
#pragma unroll
    for (int r = 0; r < 4; r++) {
        int orow = row0 + kgrp * 4 + r;
        if (orow < N_NODES)
            t[(size_t)orow * H1 + fcol] = (unsigned short)f2bf_rne(acc[r]);
    }
}

// ---------------- launch 2: g[r] += val * t[c] (at the atomic wall) -------
// 8 lanes/edge, one pk-bf16 atomic per lane -> exactly one random atomic
// line-transaction per edge; measured wall = 20G line-transactions/s.
__global__ __launch_bounds__(256) void k_edge(const int* __restrict__ rows,
                                              const int* __restrict__ cols,
                                              const float* __restrict__ vals,
                                              const unsigned int* __restrict__ tb,
                                              unsigned int* __restrict__ g2, int E) {
    int tid = blockIdx.x * 256 + threadIdx.x;
    int e = tid >> 3;
    int f2 = tid & 7;
    if (e >= E) return;
    int r = rows[e];
    int c = cols[e];
    float v = vals[e];
    unsigned int tv = tb[c * 8 + f2];
    unsigned int pk = pack_bf16(v * bf_lo(tv), v * bf_hi(tv));
    unsigned int* addr = g2 + (r * 8 + f2);
    asm volatile("global_atomic_pk_add_bf16 %0, %1, off"
                 :: "v"(addr), "v"(pk) : "memory");
}

// ---------------- launch 3: s[f]=sum_e val*relu(g[col]); last block: out ---
__global__ __launch_bounds__(256) void k_s2out(const int* __restrict__ cols,
                                               const float* __restrict__ vals,
                                               const unsigned int* __restrict__ g2,
                                               float* __restrict__ s,
                                               unsigned int* __restrict__ flag,
                                               const float* __restrict__ W2,
                                               const float* __restrict__ w_out,
                                               const float* __restrict__ b_out,
                                               float* __restrict__ out, int E) {
    const int tid = threadIdx.x;
    const int f2 = tid & 7;
    int idx    = (blockIdx.x * 256 + tid) >> 3;
    int stride = (gridDim.x * 256) >> 3;
    float accl = 0.f, acch = 0.f;
    for (int e = idx; e < E; e += stride) {
        int c = cols[e];
        float v = vals[e];
        unsigned int gv = g2[c * 8 + f2];
        accl = fmaf(v, fmaxf(bf_lo(gv), 0.f), accl);
        acch = fmaf(v, fmaxf(bf_hi(gv), 0.f), acch);
    }
    accl += __shfl_xor(accl, 8, 64);
    accl += __shfl_xor(accl, 16, 64);
    accl += __shfl_xor(accl, 32, 64);
    acch += __shfl_xor(acch, 8, 64);
    acch += __shfl_xor(acch, 16, 64);
    acch += __shfl_xor(acch, 32, 64);
    __shared__ float red[4][16];
    __shared__ int slast;
    int lane = tid & 63, wid = tid >> 6;
    if (lane < 8) { red[wid][2 * lane] = accl; red[wid][2 * lane + 1] = acch; }
    __syncthreads();
    if (tid < 16) {
        float v = red[0][tid] + red[1][tid] + red[2][tid] + red[3][tid];
        atomicAdd(&s[tid], v);
    }
    // ---- last-block-done detection, then fused k_out ----
    if (tid == 0) {
        __threadfence();                          // make s-adds visible
        unsigned int old = atomicAdd(flag, 1u);
        slast = (old == gridDim.x - 1) ? 1 : 0;
    }
    __syncthreads();
    if (slast && tid < 64) {
        // coherent read of s via atomic RMW (bypasses stale local caches)
        float sv = (tid < H1) ? atomicAdd(&s[tid], 0.f) : 0.f;
        float m = 0.f;
        if (tid < H2) {
            float v = 0.f;
#pragma unroll
            for (int f1 = 0; f1 < H1; f1++)
                v = fmaf(__shfl(sv, f1, 64), W2[f1 * H2 + tid], v);
            m = v * w_out[tid];
        }
        for (int off = 32; off; off >>= 1) m += __shfl_down(m, off, 64);
        if (tid == 0) out[0] = 1.f / (1.f + expf(-(m + b_out[0])));
    }
}

extern "C" void kernel_launch(void* const* d_in, const int* in_sizes, int n_in,
                              void* d_out, int out_size, void* d_ws, size_t ws_size,
                              hipStream_t stream) {
    const float* x         = (const float*)d_in[0];
    const float* edge_vals = (const float*)d_in[1];
    const float* W1        = (const float*)d_in[2];
    const float* W2        = (const float*)d_in[3];
    const float* w_out     = (const float*)d_in[4];
    const float* b_out     = (const float*)d_in[5];
    const int*   edge_rows = (const int*)d_in[6];
    const int*   edge_cols = (const int*)d_in[7];
    float* out = (float*)d_out;

    const int E = in_sizes[1];   // 3.2M

    // workspace layout (bytes):
    //   t   (bf16): [0,         3,200,000)
    //   g2  (bf16): [3,200,000, 6,400,000)   zeroed in k_xw1z
    //   s   (fp32): [6,400,000, 6,400,064)   zeroed in k_xw1z
    //   flag(u32):  [6,400,128, 6,400,132)   zeroed in k_xw1z
    char* ws = (char*)d_ws;
    unsigned short* t    = (unsigned short*)(ws);
    unsigned int*   g2   = (unsigned int*)(ws + 3200000);
    float*          s    = (float*)(ws + 6400000);
    unsigned int*   flag = (unsigned int*)(ws + 6400128);

    k_xw1z<<<NT1, 256, 0, stream>>>(x, W1, t, (float4*)g2, s, flag);

    long long edge_threads = (long long)E * 8;
    k_edge<<<(int)((edge_threads + 255) / 256), 256, 0, stream>>>(
        edge_rows, edge_cols, edge_vals, (const unsigned int*)t, g2, E);

    k_s2out<<<1024, 256, 0, stream>>>(edge_cols, edge_vals, g2, s, flag,
                                      W2, w_out, b_out, out, E);
}